// Round 1
// baseline (373.877 us; speedup 1.0000x reference)
//
#include <hip/hip_runtime.h>

typedef __bf16 bf16x8 __attribute__((ext_vector_type(8)));
typedef float f32x4 __attribute__((ext_vector_type(4)));

constexpr int Bc = 2, Sc = 2048, Hc = 16, Dc = 64;
constexpr int QBLK = 64, KVBLK = 64;
constexpr int ROWSTR = 3 * Hc * Dc;  // 3072 floats between consecutive s for fixed (b,h,comp)

// MFMA f32_16x16x32_bf16 layouts (verified, learn_hip m89/m97):
//   A[m][k]: lane l, elem j -> m = l&15,        k = 8*(l>>4) + j
//   B[k][n]: lane l, elem j -> k = 8*(l>>4)+j,  n = l&15
//   C/D[m][n]: lane l, reg r -> m = (l>>4)*4+r, n = l&15

__global__ __launch_bounds__(256)
void fattn_kernel(const float* __restrict__ qkv, float* __restrict__ out) {
  const int tile_q = blockIdx.x;       // 0..31
  const int bh = blockIdx.y;           // 0..31
  const int b = bh >> 4, h = bh & 15;

  const int tid = threadIdx.x;
  const int wave = tid >> 6;
  const int lane = tid & 63;
  const int lg = lane >> 4;            // 0..3
  const int li = lane & 15;            // 0..15

  const int q0 = tile_q * QBLK;
  const int qw = q0 + wave * 16;       // this wave's first q row

  const float* qp = qkv + (size_t)b * Sc * ROWSTR + h * Dc;
  const float* kp = qp + Hc * Dc;
  const float* vp = qp + 2 * Hc * Dc;

  // V^T tile [d=64][kv=64] bf16 (swizzled), per-wave P [16][64] bf16 (swizzled)
  __shared__ __align__(16) char vt_s[Dc * KVBLK * 2];
  __shared__ __align__(16) char pl_s[4][16 * KVBLK * 2];

  // ---- Q fragments, pre-scaled by 1/sqrt(D) ----
  bf16x8 qfrag[2];
  {
    const float* qrow = qp + (size_t)(qw + li) * ROWSTR + 8 * lg;
#pragma unroll
    for (int fi = 0; fi < 2; ++fi) {
      f32x4 f0 = *reinterpret_cast<const f32x4*>(qrow + 32 * fi);
      f32x4 f1 = *reinterpret_cast<const f32x4*>(qrow + 32 * fi + 4);
      bf16x8 q;
#pragma unroll
      for (int j = 0; j < 4; ++j) {
        q[j]     = (__bf16)(f0[j] * 0.125f);
        q[j + 4] = (__bf16)(f1[j] * 0.125f);
      }
      qfrag[fi] = q;
    }
  }

  f32x4 oacc[4];
#pragma unroll
  for (int n = 0; n < 4; ++n) oacc[n] = f32x4{0.f, 0.f, 0.f, 0.f};
  float mrow[4], lrow[4];
#pragma unroll
  for (int r = 0; r < 4; ++r) { mrow[r] = -1e30f; lrow[r] = 0.f; }

  const int ntiles = tile_q + 1;
  for (int t = 0; t < ntiles; ++t) {
    const int kv0 = t * KVBLK;

    // ---- cooperative stage V^T (f32 global -> bf16 LDS, transposed, swizzled) ----
#pragma unroll
    for (int i = tid; i < KVBLK * (Dc / 4); i += 256) {  // 1024 float4-loads, 4/thread
      int r  = i >> 4;           // kv row 0..63
      int c4 = (i & 15) * 4;     // d col start
      f32x4 v4 = *reinterpret_cast<const f32x4*>(vp + (size_t)(kv0 + r) * ROWSTR + c4);
#pragma unroll
      for (int j = 0; j < 4; ++j) {
        int row  = c4 + j;                       // d index = LDS row
        int byte = (row * KVBLK + r) * 2;
        byte ^= (row & 7) << 4;                  // XOR swizzle
        *reinterpret_cast<__bf16*>(vt_s + byte) = (__bf16)v4[j];
      }
    }
    __syncthreads();

    // ---- QK^T: S[q 16][kv 64] ----
    f32x4 sacc[4];
#pragma unroll
    for (int n = 0; n < 4; ++n) sacc[n] = f32x4{0.f, 0.f, 0.f, 0.f};
#pragma unroll
    for (int n = 0; n < 4; ++n) {
      const float* kr = kp + (size_t)(kv0 + 16 * n + li) * ROWSTR + 8 * lg;
#pragma unroll
      for (int fi = 0; fi < 2; ++fi) {
        f32x4 f0 = *reinterpret_cast<const f32x4*>(kr + 32 * fi);
        f32x4 f1 = *reinterpret_cast<const f32x4*>(kr + 32 * fi + 4);
        bf16x8 kb;
#pragma unroll
        for (int j = 0; j < 4; ++j) {
          kb[j]     = (__bf16)f0[j];
          kb[j + 4] = (__bf16)f1[j];
        }
        sacc[n] = __builtin_amdgcn_mfma_f32_16x16x32_bf16(qfrag[fi], kb, sacc[n], 0, 0, 0);
      }
    }

    // ---- causal mask (only the diagonal tile can have masked entries) ----
    if (t == ntiles - 1) {
#pragma unroll
      for (int n = 0; n < 4; ++n)
#pragma unroll
        for (int r = 0; r < 4; ++r)
          if (kv0 + 16 * n + li > qw + 4 * lg + r) sacc[n][r] = -1e30f;
    }

    // ---- online softmax ----
    float pm[4];
#pragma unroll
    for (int r = 0; r < 4; ++r)
      pm[r] = fmaxf(fmaxf(sacc[0][r], sacc[1][r]), fmaxf(sacc[2][r], sacc[3][r]));
#pragma unroll
    for (int msk = 1; msk <= 8; msk <<= 1)
#pragma unroll
      for (int r = 0; r < 4; ++r)
        pm[r] = fmaxf(pm[r], __shfl_xor(pm[r], msk, 64));

    float scl[4], lsum[4];
#pragma unroll
    for (int r = 0; r < 4; ++r) {
      float mnew = fmaxf(mrow[r], pm[r]);
      scl[r]  = __expf(mrow[r] - mnew);
      mrow[r] = mnew;
      lsum[r] = 0.f;
    }
#pragma unroll
    for (int n = 0; n < 4; ++n)
#pragma unroll
      for (int r = 0; r < 4; ++r) {
        float p = __expf(sacc[n][r] - mrow[r]);
        sacc[n][r] = p;
        lsum[r] += p;
      }
#pragma unroll
    for (int msk = 1; msk <= 8; msk <<= 1)
#pragma unroll
      for (int r = 0; r < 4; ++r)
        lsum[r] += __shfl_xor(lsum[r], msk, 64);
#pragma unroll
    for (int r = 0; r < 4; ++r) lrow[r] = lrow[r] * scl[r] + lsum[r];
#pragma unroll
    for (int n = 0; n < 4; ++n)
#pragma unroll
      for (int r = 0; r < 4; ++r) oacc[n][r] *= scl[r];

    // ---- P -> per-wave LDS (bf16, swizzled); wave-local, no barrier needed ----
    char* pw = pl_s[wave];
#pragma unroll
    for (int n = 0; n < 4; ++n)
#pragma unroll
      for (int r = 0; r < 4; ++r) {
        int row  = 4 * lg + r;            // q-local row
        int col  = 16 * n + li;           // kv col
        int byte = (row * KVBLK + col) * 2;
        byte ^= (row & 7) << 4;
        *reinterpret_cast<__bf16*>(pw + byte) = (__bf16)sacc[n][r];
      }

    // ---- PV: O[q 16][d 64] += P[16][64] * V[64][64] ----
#pragma unroll
    for (int ks = 0; ks < 2; ++ks) {
      int pbyte = (li * KVBLK + 32 * ks + 8 * lg) * 2;
      pbyte ^= (li & 7) << 4;
      bf16x8 pa = *reinterpret_cast<const bf16x8*>(pw + pbyte);
#pragma unroll
      for (int n = 0; n < 4; ++n) {
        int row   = 16 * n + li;          // d = LDS row of V^T
        int vbyte = (row * KVBLK + 32 * ks + 8 * lg) * 2;
        vbyte ^= (row & 7) << 4;
        bf16x8 vb = *reinterpret_cast<const bf16x8*>(vt_s + vbyte);
        oacc[n] = __builtin_amdgcn_mfma_f32_16x16x32_bf16(pa, vb, oacc[n], 0, 0, 0);
      }
    }
    __syncthreads();  // vt_s is overwritten by next iteration's staging
  }

  // ---- epilogue: normalize and store ----
#pragma unroll
  for (int r = 0; r < 4; ++r) {
    float inv  = 1.0f / lrow[r];
    int   qrow = qw + 4 * lg + r;
    float* op  = out + ((size_t)(b * Sc + qrow) * Hc + h) * Dc;
#pragma unroll
    for (int n = 0; n < 4; ++n)
      op[16 * n + li] = oacc[n][r] * inv;
  }
}

extern "C" void kernel_launch(void* const* d_in, const int* in_sizes, int n_in,
                              void* d_out, int out_size, void* d_ws, size_t ws_size,
                              hipStream_t stream) {
  const float* qkv = (const float*)d_in[0];
  float* out = (float*)d_out;
  dim3 grid(Sc / QBLK, Bc * Hc);   // (32, 32)
  fattn_kernel<<<grid, 256, 0, stream>>>(qkv, out);
}

// Round 2
// 98.960 us; speedup vs baseline: 3.7780x; 3.7780x over previous
//
#include <hip/hip_runtime.h>

typedef __bf16 bf16x8 __attribute__((ext_vector_type(8)));
typedef float f32x4 __attribute__((ext_vector_type(4)));

constexpr int Bc = 2, Sc = 2048, Hc = 16, Dc = 64;
constexpr int QBLK = 64, KVBLK = 64;
constexpr int NT = Sc / QBLK;        // 32 q-tiles
constexpr int ROWSTR = 3 * Hc * Dc;  // 3072 floats between consecutive s

// MFMA f32_16x16x32_bf16 layouts (learn_hip m89/m97):
//   A[m][k]: lane l, elem j -> m = l&15,        k = 8*(l>>4) + j
//   B[k][n]: lane l, elem j -> k = 8*(l>>4)+j,  n = l&15
//   C/D[m][n]: lane l, reg r -> m = (l>>4)*4+r, n = l&15

__global__ __launch_bounds__(256)
void fattn_kernel(const float* __restrict__ qkv, float* __restrict__ out) {
  const int xlow  = blockIdx.x;        // 0..15
  const int xhigh = NT - 1 - xlow;     // 31..16  (work per block constant: 33 steps)
  const int bh = blockIdx.y;
  const int b = bh >> 4, h = bh & 15;

  const int tid  = threadIdx.x;
  const int wave = tid >> 6;
  const int lane = tid & 63;
  const int lg = lane >> 4;            // 0..3
  const int li = lane & 15;            // 0..15

  const float* qp = qkv + (size_t)b * Sc * ROWSTR + h * Dc;
  const float* kp = qp + Hc * Dc;
  const float* vp = qp + 2 * Hc * Dc;

  // K tile [kv][d] bf16 swizzled; V^T tile [d][kv] bf16 swizzled; per-wave P
  __shared__ __align__(16) char k_s[KVBLK * Dc * 2];
  __shared__ __align__(16) char vt_s[Dc * KVBLK * 2];
  __shared__ __align__(16) char pl_s[4][16 * KVBLK * 2];
  char* pw = pl_s[wave];

  // ---- Q fragments for both q-tiles, pre-scaled by 1/sqrt(D) ----
  const int qwL = xlow * QBLK + wave * 16;
  const int qwH = xhigh * QBLK + wave * 16;
  bf16x8 qfL[2], qfH[2];
  {
    const float* qrL = qp + (size_t)(qwL + li) * ROWSTR + 8 * lg;
    const float* qrH = qp + (size_t)(qwH + li) * ROWSTR + 8 * lg;
#pragma unroll
    for (int fi = 0; fi < 2; ++fi) {
      f32x4 a0 = *(const f32x4*)(qrL + 32 * fi);
      f32x4 a1 = *(const f32x4*)(qrL + 32 * fi + 4);
      f32x4 b0 = *(const f32x4*)(qrH + 32 * fi);
      f32x4 b1 = *(const f32x4*)(qrH + 32 * fi + 4);
      bf16x8 qa, qb;
#pragma unroll
      for (int j = 0; j < 4; ++j) {
        qa[j] = (__bf16)(a0[j] * 0.125f); qa[j + 4] = (__bf16)(a1[j] * 0.125f);
        qb[j] = (__bf16)(b0[j] * 0.125f); qb[j + 4] = (__bf16)(b1[j] * 0.125f);
      }
      qfL[fi] = qa; qfH[fi] = qb;
    }
  }

  f32x4 oL[4], oH[4];
  float mLr[4], lLr[4], mHr[4], lHr[4];
#pragma unroll
  for (int n = 0; n < 4; ++n) { oL[n] = f32x4{0,0,0,0}; oH[n] = f32x4{0,0,0,0}; }
#pragma unroll
  for (int r = 0; r < 4; ++r) { mLr[r] = -1e30f; lLr[r] = 0.f; mHr[r] = -1e30f; lHr[r] = 0.f; }

  // one online-softmax + PV step for one q-tile against the staged kv tile
  auto tile_step = [&](int kv0, bool diag, int qw, bf16x8* qf,
                       f32x4* oacc, float* mrow, float* lrow) {
    // QK^T from LDS K tile
    f32x4 sacc[4];
#pragma unroll
    for (int n = 0; n < 4; ++n) sacc[n] = f32x4{0, 0, 0, 0};
    __builtin_amdgcn_s_setprio(1);
#pragma unroll
    for (int n = 0; n < 4; ++n) {
      const int krow = 16 * n + li;
#pragma unroll
      for (int fi = 0; fi < 2; ++fi) {
        const int kb_byte = (krow * 128 + fi * 64 + lg * 16) ^ ((krow & 7) << 4);
        bf16x8 kb = *(const bf16x8*)(k_s + kb_byte);
        sacc[n] = __builtin_amdgcn_mfma_f32_16x16x32_bf16(qf[fi], kb, sacc[n], 0, 0, 0);
      }
    }
    __builtin_amdgcn_s_setprio(0);

    if (diag) {
#pragma unroll
      for (int n = 0; n < 4; ++n)
#pragma unroll
        for (int r = 0; r < 4; ++r)
          if (kv0 + 16 * n + li > qw + 4 * lg + r) sacc[n][r] = -1e30f;
    }

    // online softmax
    float pm[4];
#pragma unroll
    for (int r = 0; r < 4; ++r)
      pm[r] = fmaxf(fmaxf(sacc[0][r], sacc[1][r]), fmaxf(sacc[2][r], sacc[3][r]));
#pragma unroll
    for (int msk = 1; msk <= 8; msk <<= 1)
#pragma unroll
      for (int r = 0; r < 4; ++r)
        pm[r] = fmaxf(pm[r], __shfl_xor(pm[r], msk, 64));

    float scl[4], lsum[4];
#pragma unroll
    for (int r = 0; r < 4; ++r) {
      float mnew = fmaxf(mrow[r], pm[r]);
      scl[r] = __expf(mrow[r] - mnew);
      mrow[r] = mnew;
      lsum[r] = 0.f;
    }
#pragma unroll
    for (int n = 0; n < 4; ++n)
#pragma unroll
      for (int r = 0; r < 4; ++r) {
        float p = __expf(sacc[n][r] - mrow[r]);
        sacc[n][r] = p;
        lsum[r] += p;
      }
#pragma unroll
    for (int msk = 1; msk <= 8; msk <<= 1)
#pragma unroll
      for (int r = 0; r < 4; ++r)
        lsum[r] += __shfl_xor(lsum[r], msk, 64);
#pragma unroll
    for (int r = 0; r < 4; ++r) lrow[r] = lrow[r] * scl[r] + lsum[r];
#pragma unroll
    for (int n = 0; n < 4; ++n)
#pragma unroll
      for (int r = 0; r < 4; ++r) oacc[n][r] *= scl[r];

    // P -> per-wave LDS (bf16, swizzled); wave-local, no barrier needed
#pragma unroll
    for (int n = 0; n < 4; ++n)
#pragma unroll
      for (int r = 0; r < 4; ++r) {
        const int row = 4 * lg + r;
        const int col = 16 * n + li;
        int byte = (row * KVBLK + col) * 2;
        byte ^= (row & 7) << 4;
        *(__bf16*)(pw + byte) = (__bf16)sacc[n][r];
      }

    // PV from LDS V^T tile
    __builtin_amdgcn_s_setprio(1);
#pragma unroll
    for (int ks = 0; ks < 2; ++ks) {
      int pbyte = (li * KVBLK + 32 * ks + 8 * lg) * 2;
      pbyte ^= (li & 7) << 4;
      bf16x8 pa = *(const bf16x8*)(pw + pbyte);
#pragma unroll
      for (int n = 0; n < 4; ++n) {
        const int row = 16 * n + li;
        int vbyte = (row * KVBLK + 32 * ks + 8 * lg) * 2;
        vbyte ^= (row & 7) << 4;
        bf16x8 vb = *(const bf16x8*)(vt_s + vbyte);
        oacc[n] = __builtin_amdgcn_mfma_f32_16x16x32_bf16(pa, vb, oacc[n], 0, 0, 0);
      }
    }
    __builtin_amdgcn_s_setprio(0);
  };

  for (int t = 0; t <= xhigh; ++t) {
    const int kv0 = t * KVBLK;

    // ---- cooperative staging: K row-major, V transposed (both bf16, swizzled) ----
#pragma unroll
    for (int it = 0; it < 2; ++it) {
      const int u = tid + it * 256;          // 512 units of 8 floats
      const int r = u >> 3, g = u & 7;
      const float* ksrc = kp + (size_t)(kv0 + r) * ROWSTR + g * 8;
      f32x4 k0 = *(const f32x4*)ksrc;
      f32x4 k1 = *(const f32x4*)(ksrc + 4);
      bf16x8 kb;
#pragma unroll
      for (int j = 0; j < 4; ++j) { kb[j] = (__bf16)k0[j]; kb[j + 4] = (__bf16)k1[j]; }
      int kbyte = (r * 128 + g * 16) ^ ((r & 7) << 4);
      *(bf16x8*)(k_s + kbyte) = kb;

      const float* vsrc = vp + (size_t)(kv0 + r) * ROWSTR + g * 8;
      f32x4 v0 = *(const f32x4*)vsrc;
      f32x4 v1 = *(const f32x4*)(vsrc + 4);
#pragma unroll
      for (int j = 0; j < 8; ++j) {
        const int d = g * 8 + j;
        const float val = (j < 4) ? v0[j] : v1[j - 4];
        int vbyte = (d * 128 + r * 2) ^ ((d & 7) << 4);
        *(__bf16*)(vt_s + vbyte) = (__bf16)val;
      }
    }
    __syncthreads();

    tile_step(kv0, t == xhigh, qwH, qfH, oH, mHr, lHr);
    if (t <= xlow)
      tile_step(kv0, t == xlow, qwL, qfL, oL, mLr, lLr);

    __syncthreads();
  }

  // ---- epilogue: normalize and store both q-tiles ----
#pragma unroll
  for (int r = 0; r < 4; ++r) {
    const float invH = 1.0f / lHr[r];
    const float invL = 1.0f / lLr[r];
    float* opH = out + ((size_t)(b * Sc + qwH + 4 * lg + r) * Hc + h) * Dc;
    float* opL = out + ((size_t)(b * Sc + qwL + 4 * lg + r) * Hc + h) * Dc;
#pragma unroll
    for (int n = 0; n < 4; ++n) {
      opH[16 * n + li] = oH[n][r] * invH;
      opL[16 * n + li] = oL[n][r] * invL;
    }
  }
}

extern "C" void kernel_launch(void* const* d_in, const int* in_sizes, int n_in,
                              void* d_out, int out_size, void* d_ws, size_t ws_size,
                              hipStream_t stream) {
  const float* qkv = (const float*)d_in[0];
  float* out = (float*)d_out;
  dim3 grid(NT / 2, Bc * Hc);   // (16, 32)
  fattn_kernel<<<grid, 256, 0, stream>>>(qkv, out);
}